// Round 8
// baseline (1143.605 us; speedup 1.0000x reference)
//
#include <hip/hip_runtime.h>
#include <cstdint>

#define NN 50000
#define EE 800000
#define DIN 128
#define DD 256
#define DOUT 64
#define NLAYERS 3
#define LN_EPS 1e-5f
#define NB_SCAN ((NN + 255) / 256)

typedef __attribute__((ext_vector_type(8))) _Float16 h8;  // fp16 MFMA fragment (4 VGPR)
typedef __attribute__((ext_vector_type(4))) _Float16 h4;
typedef __attribute__((ext_vector_type(4))) float f4;     // MFMA accumulator

__device__ __forceinline__ float red16(float v) {  // reduce across lane&15 group
  v += __shfl_xor(v, 1, 64);
  v += __shfl_xor(v, 2, 64);
  v += __shfl_xor(v, 4, 64);
  v += __shfl_xor(v, 8, 64);
  return v;
}

// fp16 2-limb split: a = h1 + h2 + O(2^-22 |a|); each limb product is exact in
// fp32 (11x11-bit mantissas), so 3-term MFMA reconstruction is fp32-grade.
__device__ __forceinline__ void splith(const float4& a, const float4& b, h8& p1, h8& p2) {
  float t[8] = {a.x, a.y, a.z, a.w, b.x, b.y, b.z, b.w};
#pragma unroll
  for (int i = 0; i < 8; ++i) {
    _Float16 x = (_Float16)t[i];
    p1[i] = x;
    p2[i] = (_Float16)(t[i] - (float)x);
  }
}

// ---- CSR build (edge_index constant per call; rebuilt every launch) ----
__global__ void k_zero_deg(int* __restrict__ deg) {
  int i = blockIdx.x * 256 + threadIdx.x;
  if (i < NN) deg[i] = 0;
}

__global__ void k_deg(const int* __restrict__ ei, int* __restrict__ deg) {
  int e = blockIdx.x * 256 + threadIdx.x;
  if (e < EE) atomicAdd(&deg[ei[e]], 1);
}

__global__ __launch_bounds__(256) void k_scan1(const int* __restrict__ deg,
                                               int* __restrict__ bsum) {
  __shared__ int sm[256];
  const int t = threadIdx.x;
  int i = blockIdx.x * 256 + t;
  sm[t] = (i < NN) ? deg[i] : 0;
  __syncthreads();
  for (int off = 128; off > 0; off >>= 1) {
    if (t < off) sm[t] += sm[t + off];
    __syncthreads();
  }
  if (t == 0) bsum[blockIdx.x] = sm[0];
}

__global__ __launch_bounds__(256) void k_scan2(const int* __restrict__ bsum,
                                               int* __restrict__ boff,
                                               int* __restrict__ rowptr) {
  __shared__ int sm[256];
  const int t = threadIdx.x;
  int v = (t < NB_SCAN) ? bsum[t] : 0;
  sm[t] = v;
  __syncthreads();
  for (int off = 1; off < 256; off <<= 1) {
    int x = (t >= off) ? sm[t - off] : 0;
    __syncthreads();
    sm[t] += x;
    __syncthreads();
  }
  if (t < NB_SCAN) boff[t] = sm[t] - v;  // exclusive prefix
  if (t == 0) rowptr[NN] = sm[255];      // total edge count
}

__global__ __launch_bounds__(256) void k_scan3(const int* __restrict__ deg,
                                               const int* __restrict__ boff,
                                               int* __restrict__ rowptr,
                                               int* __restrict__ cursor) {
  __shared__ int sm[256];
  const int t = threadIdx.x;
  int i = blockIdx.x * 256 + t;
  int v = (i < NN) ? deg[i] : 0;
  sm[t] = v;
  __syncthreads();
  for (int off = 1; off < 256; off <<= 1) {
    int x = (t >= off) ? sm[t - off] : 0;
    __syncthreads();
    sm[t] += x;
    __syncthreads();
  }
  if (i < NN) {
    int r = boff[blockIdx.x] + sm[t] - v;
    rowptr[i] = r;
    cursor[i] = r;
  }
}

__global__ void k_fill(const int* __restrict__ ei, int* __restrict__ cursor,
                       int* __restrict__ csr_v) {
  int e = blockIdx.x * 256 + threadIdx.x;
  if (e >= EE) return;
  int u = ei[e], v = ei[EE + e];
  int slot = atomicAdd(&cursor[u], 1);
  csr_v[slot] = v;
}

// conv weight prep, all layers: [W_root;W_agg] -> [l][n][k] fp16 limbs, K=512
__global__ void k_prep_conv(const float* __restrict__ Wr, const float* __restrict__ Wa,
                            _Float16* __restrict__ W1, _Float16* __restrict__ W2) {
  int idx = blockIdx.x * 256 + threadIdx.x;
  if (idx >= NLAYERS * DD * 2 * DD) return;
  int l = idx >> 17;  // 256*512 = 2^17
  int rem = idx & 131071;
  int n = rem >> 9, k = rem & 511;
  float w = (k < DD) ? Wr[((size_t)l * DD + k) * DD + n]
                     : Wa[((size_t)l * DD + (k - DD)) * DD + n];
  _Float16 x = (_Float16)w;
  W1[idx] = x;
  W2[idx] = (_Float16)(w - (float)x);
}

// enc + dec weight prep: -> [n][k] fp16 limbs
__global__ void k_prep_ed(const float* __restrict__ We, const float* __restrict__ Wd,
                          _Float16* __restrict__ E1, _Float16* __restrict__ E2,
                          _Float16* __restrict__ D1, _Float16* __restrict__ D2) {
  int idx = blockIdx.x * 256 + threadIdx.x;
  if (idx < DIN * DD) {
    int n = idx / DIN, k = idx - n * DIN;
    float w = We[(size_t)k * DD + n];
    _Float16 x = (_Float16)w;
    E1[idx] = x;
    E2[idx] = (_Float16)(w - (float)x);
  } else if (idx < DIN * DD + DD * DOUT) {
    int j = idx - DIN * DD;
    int n = j / DD, k = j - n * DD;
    float w = Wd[(size_t)k * DOUT + n];
    _Float16 x = (_Float16)w;
    D1[j] = x;
    D2[j] = (_Float16)(w - (float)x);
  }
}

// gates: thread per node; gather SA over in-neighbors, add root+bias+gumbel, argmax
__global__ __launch_bounds__(256) void k_gates_csr(
    const int* __restrict__ rowptr, const int* __restrict__ csr_v,
    const float* __restrict__ SR, const float* __restrict__ SA,
    const float* __restrict__ gn, const float* __restrict__ b_in,
    const float* __restrict__ b_out, unsigned char* __restrict__ gin,
    unsigned char* __restrict__ gout, int l) {
  int u = blockIdx.x * 256 + threadIdx.x;
  if (u >= NN) return;
  int beg = rowptr[u], end = rowptr[u + 1];
  float4 a = make_float4(0.f, 0.f, 0.f, 0.f);
  for (int j = beg; j < end; ++j) {
    int v = csr_v[j];
    float4 s = *(const float4*)(SA + (size_t)v * 4);
    a.x += s.x; a.y += s.y; a.z += s.z; a.w += s.w;
  }
  float4 r = *(const float4*)(SR + (size_t)u * 4);
  const float* gi = gn + ((size_t)(l * 2 + 0) * NN + u) * 2;
  const float* go = gn + ((size_t)(l * 2 + 1) * NN + u) * 2;
  float li0 = r.x + a.x + b_in[0] + gi[0];
  float li1 = r.y + a.y + b_in[1] + gi[1];
  gin[u] = (li0 >= li1) ? 1 : 0;  // argmax==0 wins ties, matches jnp.argmax
  float lo0 = r.z + a.z + b_out[0] + go[0];
  float lo1 = r.w + a.w + b_out[1] + go[1];
  gout[u] = (lo0 >= lo1) ? 1 : 0;
}

// agg (fp16 limbs) = gin[u] * sum_{v in N(u)} gout[v]*hn[v]; one wave per node.
__global__ __launch_bounds__(256) void k_wagg_csr(
    const int* __restrict__ rowptr, const int* __restrict__ csr_v,
    const unsigned char* __restrict__ gin, const unsigned char* __restrict__ gout,
    const _Float16* __restrict__ hn1, const _Float16* __restrict__ hn2,
    _Float16* __restrict__ agg1, _Float16* __restrict__ agg2) {
  const int lane = threadIdx.x & 63;
  const int u = blockIdx.x * 4 + (threadIdx.x >> 6);
  if (u >= NN) return;
  float4 acc = make_float4(0.f, 0.f, 0.f, 0.f);
  float4 acc2 = make_float4(0.f, 0.f, 0.f, 0.f);
  if (gin[u]) {
    int beg = rowptr[u], end = rowptr[u + 1];
    for (int j0 = beg; j0 < end; j0 += 64) {
      int rem = end - j0;
      int v = -1;
      if (lane < rem) v = csr_v[j0 + lane];
      int ok = (v >= 0) ? (int)gout[v] : 0;
      unsigned long long mask = __ballot(ok);
      while (mask) {
        int l0 = __builtin_ctzll(mask);
        mask &= mask - 1;
        int vv0 = __shfl(v, l0);
        const h4* p0a = (const h4*)(hn1 + (size_t)vv0 * DD + lane * 4);
        const h4* p0b = (const h4*)(hn2 + (size_t)vv0 * DD + lane * 4);
        if (mask) {
          int l1 = __builtin_ctzll(mask);
          mask &= mask - 1;
          int vv1 = __shfl(v, l1);
          const h4* p1a = (const h4*)(hn1 + (size_t)vv1 * DD + lane * 4);
          const h4* p1b = (const h4*)(hn2 + (size_t)vv1 * DD + lane * 4);
          h4 a0 = *p0a, b0 = *p0b, a1 = *p1a, b1 = *p1b;
          acc.x += (float)a0[0] + (float)b0[0]; acc.y += (float)a0[1] + (float)b0[1];
          acc.z += (float)a0[2] + (float)b0[2]; acc.w += (float)a0[3] + (float)b0[3];
          acc2.x += (float)a1[0] + (float)b1[0]; acc2.y += (float)a1[1] + (float)b1[1];
          acc2.z += (float)a1[2] + (float)b1[2]; acc2.w += (float)a1[3] + (float)b1[3];
        } else {
          h4 a0 = *p0a, b0 = *p0b;
          acc.x += (float)a0[0] + (float)b0[0]; acc.y += (float)a0[1] + (float)b0[1];
          acc.z += (float)a0[2] + (float)b0[2]; acc.w += (float)a0[3] + (float)b0[3];
        }
      }
    }
    acc.x += acc2.x; acc.y += acc2.y; acc.z += acc2.z; acc.w += acc2.w;
  }
  {
    float t[4] = {acc.x, acc.y, acc.z, acc.w};
    h4 q1, q2;
#pragma unroll
    for (int i = 0; i < 4; ++i) {
      _Float16 x = (_Float16)t[i];
      q1[i] = x;
      q2[i] = (_Float16)(t[i] - (float)x);
    }
    *(h4*)(agg1 + (size_t)u * DD + lane * 4) = q1;
    *(h4*)(agg2 + (size_t)u * DD + lane * 4) = q2;
  }
}

// LDS-free fp16-2-limb 3-term MFMA GEMM, optional fused relu+LN+limb+gate-scalar
// epilogue. A and B are pre-limbed in fragment-native [row][k] layouts, so each
// wave global-loads its fragments directly: NO LDS staging, NO barriers in the
// K-loop (the 2-barrier/K-step drain was ~74% of conv time in round 7).
// Geometry: 64 rows/block, 4 waves = 2(row) x 2(col); wave = 32 rows x NFN*16
// cols; BN = NFN*32 (=256 for fused variants -> full row per block).
template <int KTOT, int NFN, bool FUSE_LN, bool AFP32, bool DUAL, bool RELU>
__global__ __launch_bounds__(256) void k_gemm(
    const float* __restrict__ Af,                                        // AFP32 input
    const _Float16* __restrict__ A1a, const _Float16* __restrict__ A2a,  // limbs k<256
    const _Float16* __restrict__ A1b, const _Float16* __restrict__ A2b,  // limbs k>=256
    const _Float16* __restrict__ B1, const _Float16* __restrict__ B2,    // [col][KTOT]
    const float* __restrict__ bias,
    const float* __restrict__ lng, const float* __restrict__ lnb,
    const float* __restrict__ Wir, const float* __restrict__ Wia,
    const float* __restrict__ Wor, const float* __restrict__ Woa,
    _Float16* __restrict__ O1, _Float16* __restrict__ O2,  // FUSE_LN limb outputs
    float* __restrict__ SR, float* __restrict__ SA,
    float* __restrict__ Of, int ostr) {                    // plain output
  constexpr int AS = AFP32 ? KTOT : DD;  // A row stride
  const int tid = threadIdx.x;
  const int lane = tid & 63, w = tid >> 6;
  const int wr = w >> 1, wc = w & 1;
  const int fr = lane & 15, g4 = lane >> 4;
  const int fs = g4 * 8;
  const int i0 = blockIdx.x * 64;

  size_t aoff[2];
#pragma unroll
  for (int mi = 0; mi < 2; ++mi) {
    int r = i0 + wr * 32 + mi * 16 + fr;
    if (r >= NN) r = NN - 1;
    aoff[mi] = (size_t)r * AS;
  }
  size_t boff[NFN];
#pragma unroll
  for (int ni = 0; ni < NFN; ++ni)
    boff[ni] = (size_t)(wc * (NFN * 16) + ni * 16 + fr) * KTOT;

  f4 acc[2][NFN];
#pragma unroll
  for (int mi = 0; mi < 2; ++mi)
#pragma unroll
    for (int ni = 0; ni < NFN; ++ni) acc[mi][ni] = (f4){0.f, 0.f, 0.f, 0.f};

#pragma unroll 4
  for (int kt = 0; kt < KTOT / 32; ++kt) {
    const int kb = kt * 32;
    const int kl = kb + fs;
    h8 a1[2], a2[2];
    if constexpr (AFP32) {
#pragma unroll
      for (int mi = 0; mi < 2; ++mi) {
        const float* pa = Af + aoff[mi] + kl;
        float4 u = *(const float4*)(pa);
        float4 v = *(const float4*)(pa + 4);
        splith(u, v, a1[mi], a2[mi]);
      }
    } else {
      const _Float16* p1;
      const _Float16* p2;
      int ko;
      if constexpr (DUAL) {
        bool lo = kb < DD;
        p1 = lo ? A1a : A1b;
        p2 = lo ? A2a : A2b;
        ko = lo ? kl : kl - DD;
      } else {
        p1 = A1a; p2 = A2a; ko = kl;
      }
#pragma unroll
      for (int mi = 0; mi < 2; ++mi) {
        a1[mi] = *(const h8*)(p1 + aoff[mi] + ko);
        a2[mi] = *(const h8*)(p2 + aoff[mi] + ko);
      }
    }
#pragma unroll
    for (int ni = 0; ni < NFN; ++ni) {
      h8 b1 = *(const h8*)(B1 + boff[ni] + kl);
      h8 b2 = *(const h8*)(B2 + boff[ni] + kl);
#pragma unroll
      for (int mi = 0; mi < 2; ++mi) {
        acc[mi][ni] = __builtin_amdgcn_mfma_f32_16x16x32_f16(a1[mi], b1, acc[mi][ni], 0, 0, 0);
        acc[mi][ni] = __builtin_amdgcn_mfma_f32_16x16x32_f16(a1[mi], b2, acc[mi][ni], 0, 0, 0);
        acc[mi][ni] = __builtin_amdgcn_mfma_f32_16x16x32_f16(a2[mi], b1, acc[mi][ni], 0, 0, 0);
      }
    }
  }

  // C/D layout: col = lane&15 (+ni*16+wc*NFN*16), row = (lane>>4)*4 + reg (m89)
  if constexpr (FUSE_LN) {
    // fused: relu -> LN across the full 256-col row -> fp16 limb store -> gate dots
    __shared__ float rsum[64][2], rsq[64][2];
    __shared__ float rdots[64][2][8];
#pragma unroll
    for (int mi = 0; mi < 2; ++mi)
#pragma unroll
      for (int ni = 0; ni < NFN; ++ni) {
        int col = wc * 128 + ni * 16 + fr;
        float bv = bias[col];
#pragma unroll
        for (int r = 0; r < 4; ++r) {
          float v = acc[mi][ni][r] + bv;
          if constexpr (RELU) v = fmaxf(v, 0.f);
          acc[mi][ni][r] = v;
        }
      }
#pragma unroll
    for (int mi = 0; mi < 2; ++mi)
#pragma unroll
      for (int r = 0; r < 4; ++r) {
        float s = 0.f, q = 0.f;
#pragma unroll
        for (int ni = 0; ni < NFN; ++ni) {
          float v = acc[mi][ni][r];
          s += v;
          q += v * v;
        }
        s = red16(s);
        q = red16(q);
        if (fr == 0) {
          int rl = wr * 32 + mi * 16 + g4 * 4 + r;
          rsum[rl][wc] = s;
          rsq[rl][wc] = q;
        }
      }
    __syncthreads();
    float mv[2][4], rv[2][4];
#pragma unroll
    for (int mi = 0; mi < 2; ++mi)
#pragma unroll
      for (int r = 0; r < 4; ++r) {
        int rl = wr * 32 + mi * 16 + g4 * 4 + r;
        float S = rsum[rl][0] + rsum[rl][1];
        float Q = rsq[rl][0] + rsq[rl][1];
        float m = S * (1.f / DD);
        float var = fmaxf(Q * (1.f / DD) - m * m, 0.f);
        mv[mi][r] = m;
        rv[mi][r] = 1.f / sqrtf(var + LN_EPS);
      }
#pragma unroll
    for (int mi = 0; mi < 2; ++mi)
#pragma unroll
      for (int ni = 0; ni < NFN; ++ni) {
        int col = wc * 128 + ni * 16 + fr;
        float g = lng[col], b = lnb[col];
#pragma unroll
        for (int r = 0; r < 4; ++r) {
          float o = (acc[mi][ni][r] - mv[mi][r]) * rv[mi][r] * g + b;
          acc[mi][ni][r] = o;
          int row = i0 + wr * 32 + mi * 16 + g4 * 4 + r;
          if (row < NN) {
            _Float16 x = (_Float16)o;
            O1[(size_t)row * DD + col] = x;
            O2[(size_t)row * DD + col] = (_Float16)(o - (float)x);
          }
        }
      }
    // gate-net dots: 8 per row (Wir/Wia/Wor/Woa, each [256][2])
#pragma unroll
    for (int mi = 0; mi < 2; ++mi) {
      float pd[4][8];
#pragma unroll
      for (int r = 0; r < 4; ++r)
#pragma unroll
        for (int j = 0; j < 8; ++j) pd[r][j] = 0.f;
#pragma unroll
      for (int ni = 0; ni < NFN; ++ni) {
        int col = wc * 128 + ni * 16 + fr;
        float2 wir = *(const float2*)(Wir + col * 2);
        float2 wia = *(const float2*)(Wia + col * 2);
        float2 wor = *(const float2*)(Wor + col * 2);
        float2 woa = *(const float2*)(Woa + col * 2);
#pragma unroll
        for (int r = 0; r < 4; ++r) {
          float o = acc[mi][ni][r];
          pd[r][0] = fmaf(o, wir.x, pd[r][0]);
          pd[r][1] = fmaf(o, wir.y, pd[r][1]);
          pd[r][2] = fmaf(o, wia.x, pd[r][2]);
          pd[r][3] = fmaf(o, wia.y, pd[r][3]);
          pd[r][4] = fmaf(o, wor.x, pd[r][4]);
          pd[r][5] = fmaf(o, wor.y, pd[r][5]);
          pd[r][6] = fmaf(o, woa.x, pd[r][6]);
          pd[r][7] = fmaf(o, woa.y, pd[r][7]);
        }
      }
#pragma unroll
      for (int r = 0; r < 4; ++r)
#pragma unroll
        for (int j = 0; j < 8; ++j) pd[r][j] = red16(pd[r][j]);
      if (fr == 0) {
#pragma unroll
        for (int r = 0; r < 4; ++r) {
          int rl = wr * 32 + mi * 16 + g4 * 4 + r;
#pragma unroll
          for (int j = 0; j < 8; ++j) rdots[rl][wc][j] = pd[r][j];
        }
      }
    }
    __syncthreads();
    if (tid < 64) {
      int row = i0 + tid;
      if (row < NN) {
        float d[8];
#pragma unroll
        for (int j = 0; j < 8; ++j) d[j] = rdots[tid][0][j] + rdots[tid][1][j];
        *(float4*)(SR + (size_t)row * 4) = make_float4(d[0], d[1], d[4], d[5]);
        *(float4*)(SA + (size_t)row * 4) = make_float4(d[2], d[3], d[6], d[7]);
      }
    }
  } else {
    // plain epilogue (decoder)
#pragma unroll
    for (int mi = 0; mi < 2; ++mi)
#pragma unroll
      for (int ni = 0; ni < NFN; ++ni) {
        int col = wc * (NFN * 16) + ni * 16 + fr;
        float bv = bias[col];
#pragma unroll
        for (int r = 0; r < 4; ++r) {
          int row = i0 + wr * 32 + mi * 16 + g4 * 4 + r;
          if (row < NN) Of[(size_t)row * ostr + col] = acc[mi][ni][r] + bv;
        }
      }
  }
}

extern "C" void kernel_launch(void* const* d_in, const int* in_sizes, int n_in,
                              void* d_out, int out_size, void* d_ws, size_t ws_size,
                              hipStream_t stream) {
  const float* x = (const float*)d_in[0];
  const int* ei = (const int*)d_in[1];
  const float* gn = (const float*)d_in[2];
  const float* W_enc = (const float*)d_in[3];
  const float* b_enc = (const float*)d_in[4];
  const float* W_root = (const float*)d_in[5];
  const float* W_agg = (const float*)d_in[6];
  const float* b_env = (const float*)d_in[7];
  const float* Wa_in_r = (const float*)d_in[8];
  const float* Wa_in_a = (const float*)d_in[9];
  const float* b_in = (const float*)d_in[10];
  const float* Wa_out_r = (const float*)d_in[11];
  const float* Wa_out_a = (const float*)d_in[12];
  const float* b_out = (const float*)d_in[13];
  // d_in[14..16] (Wt_r, Wt_a, b_t) are dead: hard gumbel = one_hot(argmax(logits+g)),
  // temp>0 never changes the argmax.
  const float* ln_g = (const float*)d_in[17];
  const float* ln_b = (const float*)d_in[18];
  const float* W_dec = (const float*)d_in[19];
  const float* b_dec = (const float*)d_in[20];
  float* out = (float*)d_out;

  float* ws = (float*)d_ws;
  size_t off = 0;
  _Float16* hnA1 = (_Float16*)(ws + off); off += (size_t)NN * DD / 2;
  _Float16* hnA2 = (_Float16*)(ws + off); off += (size_t)NN * DD / 2;
  _Float16* hnB1 = (_Float16*)(ws + off); off += (size_t)NN * DD / 2;
  _Float16* hnB2 = (_Float16*)(ws + off); off += (size_t)NN * DD / 2;
  _Float16* agg1 = (_Float16*)(ws + off); off += (size_t)NN * DD / 2;
  _Float16* agg2 = (_Float16*)(ws + off); off += (size_t)NN * DD / 2;
  float* SR = ws + off; off += (size_t)NN * 4;
  float* SA = ws + off; off += (size_t)NN * 4;
  int* rowptr = (int*)(ws + off); off += (size_t)NN + 4;
  int* csr_v = (int*)(ws + off);  off += (size_t)EE;
  unsigned char* gin = (unsigned char*)(ws + off);  off += (size_t)NN / 4;
  unsigned char* gout = (unsigned char*)(ws + off); off += (size_t)NN / 4;
  _Float16* cW1 = (_Float16*)(ws + off); off += (size_t)NLAYERS * DD * DD;  // [3][256][512]
  _Float16* cW2 = (_Float16*)(ws + off); off += (size_t)NLAYERS * DD * DD;
  _Float16* eW1 = (_Float16*)(ws + off); off += (size_t)DD * DIN / 2;       // [256][128]
  _Float16* eW2 = (_Float16*)(ws + off); off += (size_t)DD * DIN / 2;
  _Float16* dW1 = (_Float16*)(ws + off); off += (size_t)DOUT * DD / 2;      // [64][256]
  _Float16* dW2 = (_Float16*)(ws + off); off += (size_t)DOUT * DD / 2;
  if (ws_size < off * sizeof(float)) return;  // insufficient scratch -> visible failure
  // CSR-build aliases (SR/SA rewritten by the encoder epilogue after build)
  int* deg = (int*)SR;
  int* bsum = (int*)SR + NN;
  int* boffp = (int*)SR + NN + 256;
  int* cursor = (int*)SA;

  k_zero_deg<<<(NN + 255) / 256, 256, 0, stream>>>(deg);
  k_deg<<<(EE + 255) / 256, 256, 0, stream>>>(ei, deg);
  k_scan1<<<NB_SCAN, 256, 0, stream>>>(deg, bsum);
  k_scan2<<<1, 256, 0, stream>>>(bsum, boffp, rowptr);
  k_scan3<<<NB_SCAN, 256, 0, stream>>>(deg, boffp, rowptr, cursor);
  k_fill<<<(EE + 255) / 256, 256, 0, stream>>>(ei, cursor, csr_v);

  k_prep_conv<<<(NLAYERS * DD * 2 * DD + 255) / 256, 256, 0, stream>>>(W_root, W_agg, cW1, cW2);
  k_prep_ed<<<(DIN * DD + DD * DOUT + 255) / 256, 256, 0, stream>>>(W_enc, W_dec,
                                                                    eW1, eW2, dW1, dW2);

  const int gb = (NN + 63) / 64;
  // encoder fused: hn = LN(relu(x @ W_enc + b_enc)), + SR/SA
  k_gemm<DIN, 8, true, true, false, true><<<gb, 256, 0, stream>>>(
      x, nullptr, nullptr, nullptr, nullptr, eW1, eW2, b_enc,
      ln_g, ln_b, Wa_in_r, Wa_in_a, Wa_out_r, Wa_out_a,
      hnA1, hnA2, SR, SA, nullptr, 0);

  _Float16 *cur1 = hnA1, *cur2 = hnA2, *nxt1 = hnB1, *nxt2 = hnB2;
  for (int l = 0; l < NLAYERS; ++l) {
    k_gates_csr<<<(NN + 255) / 256, 256, 0, stream>>>(rowptr, csr_v, SR, SA, gn,
                                                      b_in, b_out, gin, gout, l);
    k_wagg_csr<<<(NN + 3) / 4, 256, 0, stream>>>(rowptr, csr_v, gin, gout,
                                                 cur1, cur2, agg1, agg2);
    // conv fused: hn' = LN(relu([hn|agg] @ [Wr;Wa] + b_env)), + SR/SA
    k_gemm<2 * DD, 8, true, false, true, true><<<gb, 256, 0, stream>>>(
        nullptr, cur1, cur2, agg1, agg2,
        cW1 + (size_t)l * DD * 2 * DD, cW2 + (size_t)l * DD * 2 * DD,
        b_env + (size_t)l * DD,
        ln_g, ln_b, Wa_in_r, Wa_in_a, Wa_out_r, Wa_out_a,
        nxt1, nxt2, SR, SA, nullptr, 0);
    _Float16* t1 = cur1; cur1 = nxt1; nxt1 = t1;
    _Float16* t2 = cur2; cur2 = nxt2; nxt2 = t2;
  }

  // decoder: out = hn @ W_dec + b_dec
  k_gemm<DD, 2, false, false, false, false><<<gb, 256, 0, stream>>>(
      nullptr, cur1, cur2, nullptr, nullptr, dW1, dW2, b_dec,
      nullptr, nullptr, nullptr, nullptr, nullptr, nullptr,
      nullptr, nullptr, nullptr, nullptr, out, DOUT);
}

// Round 9
// 781.821 us; speedup vs baseline: 1.4627x; 1.4627x over previous
//
#include <hip/hip_runtime.h>
#include <cstdint>

#define NN 50000
#define EE 800000
#define DIN 128
#define DD 256
#define DOUT 64
#define NLAYERS 3
#define LN_EPS 1e-5f
#define NB_SCAN ((NN + 255) / 256)

typedef __attribute__((ext_vector_type(8))) _Float16 h8;  // fp16 MFMA fragment (4 VGPR)
typedef __attribute__((ext_vector_type(4))) _Float16 h4;
typedef __attribute__((ext_vector_type(4))) float f4;     // MFMA accumulator

__device__ __forceinline__ float red16(float v) {  // reduce across lane&15 group
  v += __shfl_xor(v, 1, 64);
  v += __shfl_xor(v, 2, 64);
  v += __shfl_xor(v, 4, 64);
  v += __shfl_xor(v, 8, 64);
  return v;
}

// fp16 2-limb split: a = h1 + h2 + O(2^-22 |a|); each limb product is exact in
// fp32 (11x11-bit mantissas), so 3-term MFMA reconstruction is fp32-grade.
__device__ __forceinline__ void splith(const float4& a, const float4& b, h8& p1, h8& p2) {
  float t[8] = {a.x, a.y, a.z, a.w, b.x, b.y, b.z, b.w};
#pragma unroll
  for (int i = 0; i < 8; ++i) {
    _Float16 x = (_Float16)t[i];
    p1[i] = x;
    p2[i] = (_Float16)(t[i] - (float)x);
  }
}

// ---- CSR build (edge_index constant per call; rebuilt every launch) ----
__global__ void k_zero_deg(int* __restrict__ deg) {
  int i = blockIdx.x * 256 + threadIdx.x;
  if (i < NN) deg[i] = 0;
}

__global__ void k_deg(const int* __restrict__ ei, int* __restrict__ deg) {
  int e = blockIdx.x * 256 + threadIdx.x;
  if (e < EE) atomicAdd(&deg[ei[e]], 1);
}

__global__ __launch_bounds__(256) void k_scan1(const int* __restrict__ deg,
                                               int* __restrict__ bsum) {
  __shared__ int sm[256];
  const int t = threadIdx.x;
  int i = blockIdx.x * 256 + t;
  sm[t] = (i < NN) ? deg[i] : 0;
  __syncthreads();
  for (int off = 128; off > 0; off >>= 1) {
    if (t < off) sm[t] += sm[t + off];
    __syncthreads();
  }
  if (t == 0) bsum[blockIdx.x] = sm[0];
}

__global__ __launch_bounds__(256) void k_scan2(const int* __restrict__ bsum,
                                               int* __restrict__ boff,
                                               int* __restrict__ rowptr) {
  __shared__ int sm[256];
  const int t = threadIdx.x;
  int v = (t < NB_SCAN) ? bsum[t] : 0;
  sm[t] = v;
  __syncthreads();
  for (int off = 1; off < 256; off <<= 1) {
    int x = (t >= off) ? sm[t - off] : 0;
    __syncthreads();
    sm[t] += x;
    __syncthreads();
  }
  if (t < NB_SCAN) boff[t] = sm[t] - v;  // exclusive prefix
  if (t == 0) rowptr[NN] = sm[255];      // total edge count
}

__global__ __launch_bounds__(256) void k_scan3(const int* __restrict__ deg,
                                               const int* __restrict__ boff,
                                               int* __restrict__ rowptr,
                                               int* __restrict__ cursor) {
  __shared__ int sm[256];
  const int t = threadIdx.x;
  int i = blockIdx.x * 256 + t;
  int v = (i < NN) ? deg[i] : 0;
  sm[t] = v;
  __syncthreads();
  for (int off = 1; off < 256; off <<= 1) {
    int x = (t >= off) ? sm[t - off] : 0;
    __syncthreads();
    sm[t] += x;
    __syncthreads();
  }
  if (i < NN) {
    int r = boff[blockIdx.x] + sm[t] - v;
    rowptr[i] = r;
    cursor[i] = r;
  }
}

__global__ void k_fill(const int* __restrict__ ei, int* __restrict__ cursor,
                       int* __restrict__ csr_v) {
  int e = blockIdx.x * 256 + threadIdx.x;
  if (e >= EE) return;
  int u = ei[e], v = ei[EE + e];
  int slot = atomicAdd(&cursor[u], 1);
  csr_v[slot] = v;
}

// conv weight prep, all layers: [W_root;W_agg] -> [l][n][k] fp16 limbs, K=512
__global__ void k_prep_conv(const float* __restrict__ Wr, const float* __restrict__ Wa,
                            _Float16* __restrict__ W1, _Float16* __restrict__ W2) {
  int idx = blockIdx.x * 256 + threadIdx.x;
  if (idx >= NLAYERS * DD * 2 * DD) return;
  int l = idx >> 17;  // 256*512 = 2^17
  int rem = idx & 131071;
  int n = rem >> 9, k = rem & 511;
  float w = (k < DD) ? Wr[((size_t)l * DD + k) * DD + n]
                     : Wa[((size_t)l * DD + (k - DD)) * DD + n];
  _Float16 x = (_Float16)w;
  W1[idx] = x;
  W2[idx] = (_Float16)(w - (float)x);
}

// enc + dec weight prep: -> [n][k] fp16 limbs
__global__ void k_prep_ed(const float* __restrict__ We, const float* __restrict__ Wd,
                          _Float16* __restrict__ E1, _Float16* __restrict__ E2,
                          _Float16* __restrict__ D1, _Float16* __restrict__ D2) {
  int idx = blockIdx.x * 256 + threadIdx.x;
  if (idx < DIN * DD) {
    int n = idx / DIN, k = idx - n * DIN;
    float w = We[(size_t)k * DD + n];
    _Float16 x = (_Float16)w;
    E1[idx] = x;
    E2[idx] = (_Float16)(w - (float)x);
  } else if (idx < DIN * DD + DD * DOUT) {
    int j = idx - DIN * DD;
    int n = j / DD, k = j - n * DD;
    float w = Wd[(size_t)k * DOUT + n];
    _Float16 x = (_Float16)w;
    D1[j] = x;
    D2[j] = (_Float16)(w - (float)x);
  }
}

// gates: thread per node; gather SA over in-neighbors, add root+bias+gumbel, argmax
__global__ __launch_bounds__(256) void k_gates_csr(
    const int* __restrict__ rowptr, const int* __restrict__ csr_v,
    const float* __restrict__ SR, const float* __restrict__ SA,
    const float* __restrict__ gn, const float* __restrict__ b_in,
    const float* __restrict__ b_out, unsigned char* __restrict__ gin,
    unsigned char* __restrict__ gout, int l) {
  int u = blockIdx.x * 256 + threadIdx.x;
  if (u >= NN) return;
  int beg = rowptr[u], end = rowptr[u + 1];
  float4 a = make_float4(0.f, 0.f, 0.f, 0.f);
  for (int j = beg; j < end; ++j) {
    int v = csr_v[j];
    float4 s = *(const float4*)(SA + (size_t)v * 4);
    a.x += s.x; a.y += s.y; a.z += s.z; a.w += s.w;
  }
  float4 r = *(const float4*)(SR + (size_t)u * 4);
  const float* gi = gn + ((size_t)(l * 2 + 0) * NN + u) * 2;
  const float* go = gn + ((size_t)(l * 2 + 1) * NN + u) * 2;
  float li0 = r.x + a.x + b_in[0] + gi[0];
  float li1 = r.y + a.y + b_in[1] + gi[1];
  gin[u] = (li0 >= li1) ? 1 : 0;  // argmax==0 wins ties, matches jnp.argmax
  float lo0 = r.z + a.z + b_out[0] + go[0];
  float lo1 = r.w + a.w + b_out[1] + go[1];
  gout[u] = (lo0 >= lo1) ? 1 : 0;
}

// agg (fp16 limbs) = gin[u] * sum_{v in N(u)} gout[v]*hn[v]; one wave per node.
__global__ __launch_bounds__(256) void k_wagg_csr(
    const int* __restrict__ rowptr, const int* __restrict__ csr_v,
    const unsigned char* __restrict__ gin, const unsigned char* __restrict__ gout,
    const _Float16* __restrict__ hn1, const _Float16* __restrict__ hn2,
    _Float16* __restrict__ agg1, _Float16* __restrict__ agg2) {
  const int lane = threadIdx.x & 63;
  const int u = blockIdx.x * 4 + (threadIdx.x >> 6);
  if (u >= NN) return;
  float4 acc = make_float4(0.f, 0.f, 0.f, 0.f);
  float4 acc2 = make_float4(0.f, 0.f, 0.f, 0.f);
  if (gin[u]) {
    int beg = rowptr[u], end = rowptr[u + 1];
    for (int j0 = beg; j0 < end; j0 += 64) {
      int rem = end - j0;
      int v = -1;
      if (lane < rem) v = csr_v[j0 + lane];
      int ok = (v >= 0) ? (int)gout[v] : 0;
      unsigned long long mask = __ballot(ok);
      while (mask) {
        int l0 = __builtin_ctzll(mask);
        mask &= mask - 1;
        int vv0 = __shfl(v, l0);
        const h4* p0a = (const h4*)(hn1 + (size_t)vv0 * DD + lane * 4);
        const h4* p0b = (const h4*)(hn2 + (size_t)vv0 * DD + lane * 4);
        if (mask) {
          int l1 = __builtin_ctzll(mask);
          mask &= mask - 1;
          int vv1 = __shfl(v, l1);
          const h4* p1a = (const h4*)(hn1 + (size_t)vv1 * DD + lane * 4);
          const h4* p1b = (const h4*)(hn2 + (size_t)vv1 * DD + lane * 4);
          h4 a0 = *p0a, b0 = *p0b, a1 = *p1a, b1 = *p1b;
          acc.x += (float)a0[0] + (float)b0[0]; acc.y += (float)a0[1] + (float)b0[1];
          acc.z += (float)a0[2] + (float)b0[2]; acc.w += (float)a0[3] + (float)b0[3];
          acc2.x += (float)a1[0] + (float)b1[0]; acc2.y += (float)a1[1] + (float)b1[1];
          acc2.z += (float)a1[2] + (float)b1[2]; acc2.w += (float)a1[3] + (float)b1[3];
        } else {
          h4 a0 = *p0a, b0 = *p0b;
          acc.x += (float)a0[0] + (float)b0[0]; acc.y += (float)a0[1] + (float)b0[1];
          acc.z += (float)a0[2] + (float)b0[2]; acc.w += (float)a0[3] + (float)b0[3];
        }
      }
    }
    acc.x += acc2.x; acc.y += acc2.y; acc.z += acc2.z; acc.w += acc2.w;
  }
  {
    float t[4] = {acc.x, acc.y, acc.z, acc.w};
    h4 q1, q2;
#pragma unroll
    for (int i = 0; i < 4; ++i) {
      _Float16 x = (_Float16)t[i];
      q1[i] = x;
      q2[i] = (_Float16)(t[i] - (float)x);
    }
    *(h4*)(agg1 + (size_t)u * DD + lane * 4) = q1;
    *(h4*)(agg2 + (size_t)u * DD + lane * 4) = q2;
  }
}

// LDS-staged fp16-2-limb 3-term MFMA GEMM (round-6-proven K-loop: register
// prefetch + 2 barriers/K-step), with round-8-proven fused relu+LN+limb+gate
// epilogue. Geometry: BM=64 rows/block, 4 waves = 2(row)x2(col); wave tile
// 32 x NFN*16; BN = NFN*32 (256 for fused -> full row per block, j0 == 0).
#define LDPh 40  // halves; 80B row stride -> 2-way bank aliasing (free, m136)

template <int KTOT, int NFN, bool FUSE_LN, bool AFP32, bool DUAL, bool RELU>
__global__ __launch_bounds__(256, 3) void k_gemm(
    const float* __restrict__ Af,                                        // AFP32 input
    const _Float16* __restrict__ A1a, const _Float16* __restrict__ A2a,  // limbs k<256
    const _Float16* __restrict__ A1b, const _Float16* __restrict__ A2b,  // limbs k>=256
    const _Float16* __restrict__ B1, const _Float16* __restrict__ B2,    // [col][KTOT]
    const float* __restrict__ bias,
    const float* __restrict__ lng, const float* __restrict__ lnb,
    const float* __restrict__ Wir, const float* __restrict__ Wia,
    const float* __restrict__ Wor, const float* __restrict__ Woa,
    _Float16* __restrict__ O1, _Float16* __restrict__ O2,  // FUSE_LN limb outputs
    float* __restrict__ SR, float* __restrict__ SA,
    float* __restrict__ Of, int ostr) {                    // plain output
  constexpr int BN = NFN * 32;
  constexpr int KSTEPS = KTOT / 32;
  constexpr int NBR = BN / 64;           // B h8-loads per thread per plane
  constexpr int AS = AFP32 ? KTOT : DD;  // A row stride
  __shared__ _Float16 smem[(64 + BN) * LDPh * 2];
  _Float16* sA1 = smem;
  _Float16* sA2 = sA1 + 64 * LDPh;
  _Float16* sB1 = sA2 + 64 * LDPh;
  _Float16* sB2 = sB1 + BN * LDPh;

  const int tid = threadIdx.x;
  const int lane = tid & 63, w = tid >> 6;
  const int wr = w >> 1, wc = w & 1;
  const int fr = lane & 15, g4 = lane >> 4;
  const int fs = g4 * 8;
  const int i0 = blockIdx.x * 64;

  // staging coords: 4 threads cover one row's 32-k strip
  const int ar = tid >> 2, ak = (tid & 3) * 8;
  int garow = i0 + ar;
  if (garow >= NN) garow = NN - 1;
  const size_t aoff = (size_t)garow * AS;

  f4 acc[2][NFN];
#pragma unroll
  for (int mi = 0; mi < 2; ++mi)
#pragma unroll
    for (int ni = 0; ni < NFN; ++ni) acc[mi][ni] = (f4){0.f, 0.f, 0.f, 0.f};

  float4 fa0, fa1;
  h8 ra1, ra2;
  h8 rb1[NBR], rb2[NBR];
  {  // prefetch K-tile 0 (k in [0,32) -> low-K A source)
    if constexpr (AFP32) {
      const float* pa = Af + aoff + ak;
      fa0 = *(const float4*)(pa);
      fa1 = *(const float4*)(pa + 4);
    } else {
      ra1 = *(const h8*)(A1a + aoff + ak);
      ra2 = *(const h8*)(A2a + aoff + ak);
    }
#pragma unroll
    for (int i = 0; i < NBR; ++i) {
      size_t bo = (size_t)(ar + i * 64) * KTOT + ak;
      rb1[i] = *(const h8*)(B1 + bo);
      rb2[i] = *(const h8*)(B2 + bo);
    }
  }
  for (int kt = 0; kt < KSTEPS; ++kt) {
    __syncthreads();
    {
      int o = ar * LDPh + ak;
      if constexpr (AFP32) {
        h8 p1, p2;
        splith(fa0, fa1, p1, p2);
        *(h8*)&sA1[o] = p1;
        *(h8*)&sA2[o] = p2;
      } else {
        *(h8*)&sA1[o] = ra1;
        *(h8*)&sA2[o] = ra2;
      }
#pragma unroll
      for (int i = 0; i < NBR; ++i) {
        int ob = (ar + i * 64) * LDPh + ak;
        *(h8*)&sB1[ob] = rb1[i];
        *(h8*)&sB2[ob] = rb2[i];
      }
    }
    __syncthreads();
    if (kt < KSTEPS - 1) {  // prefetch next K-tile into registers
      int kb = (kt + 1) * 32;
      if constexpr (AFP32) {
        const float* pa = Af + aoff + kb + ak;
        fa0 = *(const float4*)(pa);
        fa1 = *(const float4*)(pa + 4);
      } else {
        const _Float16 *p1, *p2;
        int ko;
        if constexpr (DUAL) {
          bool lo = kb < DD;
          p1 = lo ? A1a : A1b;
          p2 = lo ? A2a : A2b;
          ko = lo ? kb : kb - DD;
        } else {
          p1 = A1a; p2 = A2a; ko = kb;
        }
        ra1 = *(const h8*)(p1 + aoff + ko + ak);
        ra2 = *(const h8*)(p2 + aoff + ko + ak);
      }
#pragma unroll
      for (int i = 0; i < NBR; ++i) {
        size_t bo = (size_t)(ar + i * 64) * KTOT + kb + ak;
        rb1[i] = *(const h8*)(B1 + bo);
        rb2[i] = *(const h8*)(B2 + bo);
      }
    }
    h8 a1[2], a2[2];
#pragma unroll
    for (int mi = 0; mi < 2; ++mi) {
      int r = (wr * 32 + mi * 16 + fr) * LDPh + fs;
      a1[mi] = *(const h8*)&sA1[r];
      a2[mi] = *(const h8*)&sA2[r];
    }
#pragma unroll
    for (int ni = 0; ni < NFN; ++ni) {
      int c = (wc * (NFN * 16) + ni * 16 + fr) * LDPh + fs;
      h8 b1 = *(const h8*)&sB1[c];
      h8 b2 = *(const h8*)&sB2[c];
#pragma unroll
      for (int mi = 0; mi < 2; ++mi) {
        acc[mi][ni] = __builtin_amdgcn_mfma_f32_16x16x32_f16(a1[mi], b1, acc[mi][ni], 0, 0, 0);
        acc[mi][ni] = __builtin_amdgcn_mfma_f32_16x16x32_f16(a1[mi], b2, acc[mi][ni], 0, 0, 0);
        acc[mi][ni] = __builtin_amdgcn_mfma_f32_16x16x32_f16(a2[mi], b1, acc[mi][ni], 0, 0, 0);
      }
    }
  }

  // C/D layout: col = lane&15 (+ni*16+wc*NFN*16), row = (lane>>4)*4 + reg (m89)
  if constexpr (FUSE_LN) {
    // epilogue scratch aliases the (now dead) staging LDS; barrier first
    __syncthreads();
    float* rsum = (float*)smem;           // [64][2]
    float* rsq = rsum + 128;              // [64][2]
    float* rdots = rsq + 128;             // [64][2][8]
#pragma unroll
    for (int mi = 0; mi < 2; ++mi)
#pragma unroll
      for (int ni = 0; ni < NFN; ++ni) {
        int col = wc * 128 + ni * 16 + fr;
        float bv = bias[col];
#pragma unroll
        for (int r = 0; r < 4; ++r) {
          float v = acc[mi][ni][r] + bv;
          if constexpr (RELU) v = fmaxf(v, 0.f);
          acc[mi][ni][r] = v;
        }
      }
#pragma unroll
    for (int mi = 0; mi < 2; ++mi)
#pragma unroll
      for (int r = 0; r < 4; ++r) {
        float s = 0.f, q = 0.f;
#pragma unroll
        for (int ni = 0; ni < NFN; ++ni) {
          float v = acc[mi][ni][r];
          s += v;
          q += v * v;
        }
        s = red16(s);
        q = red16(q);
        if (fr == 0) {
          int rl = wr * 32 + mi * 16 + g4 * 4 + r;
          rsum[rl * 2 + wc] = s;
          rsq[rl * 2 + wc] = q;
        }
      }
    __syncthreads();
    float mv[2][4], rv[2][4];
#pragma unroll
    for (int mi = 0; mi < 2; ++mi)
#pragma unroll
      for (int r = 0; r < 4; ++r) {
        int rl = wr * 32 + mi * 16 + g4 * 4 + r;
        float S = rsum[rl * 2] + rsum[rl * 2 + 1];
        float Q = rsq[rl * 2] + rsq[rl * 2 + 1];
        float m = S * (1.f / DD);
        float var = fmaxf(Q * (1.f / DD) - m * m, 0.f);
        mv[mi][r] = m;
        rv[mi][r] = 1.f / sqrtf(var + LN_EPS);
      }
#pragma unroll
    for (int mi = 0; mi < 2; ++mi)
#pragma unroll
      for (int ni = 0; ni < NFN; ++ni) {
        int col = wc * 128 + ni * 16 + fr;
        float g = lng[col], b = lnb[col];
#pragma unroll
        for (int r = 0; r < 4; ++r) {
          float o = (acc[mi][ni][r] - mv[mi][r]) * rv[mi][r] * g + b;
          acc[mi][ni][r] = o;
          int row = i0 + wr * 32 + mi * 16 + g4 * 4 + r;
          if (row < NN) {
            _Float16 x = (_Float16)o;
            O1[(size_t)row * DD + col] = x;
            O2[(size_t)row * DD + col] = (_Float16)(o - (float)x);
          }
        }
      }
    // gate-net dots: 8 per row (Wir/Wia/Wor/Woa, each [256][2])
#pragma unroll
    for (int mi = 0; mi < 2; ++mi) {
      float pd[4][8];
#pragma unroll
      for (int r = 0; r < 4; ++r)
#pragma unroll
        for (int j = 0; j < 8; ++j) pd[r][j] = 0.f;
#pragma unroll
      for (int ni = 0; ni < NFN; ++ni) {
        int col = wc * 128 + ni * 16 + fr;
        float2 wir = *(const float2*)(Wir + col * 2);
        float2 wia = *(const float2*)(Wia + col * 2);
        float2 wor = *(const float2*)(Wor + col * 2);
        float2 woa = *(const float2*)(Woa + col * 2);
#pragma unroll
        for (int r = 0; r < 4; ++r) {
          float o = acc[mi][ni][r];
          pd[r][0] = fmaf(o, wir.x, pd[r][0]);
          pd[r][1] = fmaf(o, wir.y, pd[r][1]);
          pd[r][2] = fmaf(o, wia.x, pd[r][2]);
          pd[r][3] = fmaf(o, wia.y, pd[r][3]);
          pd[r][4] = fmaf(o, wor.x, pd[r][4]);
          pd[r][5] = fmaf(o, wor.y, pd[r][5]);
          pd[r][6] = fmaf(o, woa.x, pd[r][6]);
          pd[r][7] = fmaf(o, woa.y, pd[r][7]);
        }
      }
#pragma unroll
      for (int r = 0; r < 4; ++r)
#pragma unroll
        for (int j = 0; j < 8; ++j) pd[r][j] = red16(pd[r][j]);
      if (fr == 0) {
#pragma unroll
        for (int r = 0; r < 4; ++r) {
          int rl = wr * 32 + mi * 16 + g4 * 4 + r;
#pragma unroll
          for (int j = 0; j < 8; ++j) rdots[(rl * 2 + wc) * 8 + j] = pd[r][j];
        }
      }
    }
    __syncthreads();
    if (tid < 64) {
      int row = i0 + tid;
      if (row < NN) {
        float d[8];
#pragma unroll
        for (int j = 0; j < 8; ++j) d[j] = rdots[tid * 16 + j] + rdots[tid * 16 + 8 + j];
        *(float4*)(SR + (size_t)row * 4) = make_float4(d[0], d[1], d[4], d[5]);
        *(float4*)(SA + (size_t)row * 4) = make_float4(d[2], d[3], d[6], d[7]);
      }
    }
  } else {
    // plain epilogue (decoder)
#pragma unroll
    for (int mi = 0; mi < 2; ++mi)
#pragma unroll
      for (int ni = 0; ni < NFN; ++ni) {
        int col = wc * (NFN * 16) + ni * 16 + fr;
        float bv = bias[col];
#pragma unroll
        for (int r = 0; r < 4; ++r) {
          int row = i0 + wr * 32 + mi * 16 + g4 * 4 + r;
          if (row < NN) Of[(size_t)row * ostr + col] = acc[mi][ni][r] + bv;
        }
      }
  }
}

extern "C" void kernel_launch(void* const* d_in, const int* in_sizes, int n_in,
                              void* d_out, int out_size, void* d_ws, size_t ws_size,
                              hipStream_t stream) {
  const float* x = (const float*)d_in[0];
  const int* ei = (const int*)d_in[1];
  const float* gn = (const float*)d_in[2];
  const float* W_enc = (const float*)d_in[3];
  const float* b_enc = (const float*)d_in[4];
  const float* W_root = (const float*)d_in[5];
  const float* W_agg = (const float*)d_in[6];
  const float* b_env = (const float*)d_in[7];
  const float* Wa_in_r = (const float*)d_in[8];
  const float* Wa_in_a = (const float*)d_in[9];
  const float* b_in = (const float*)d_in[10];
  const float* Wa_out_r = (const float*)d_in[11];
  const float* Wa_out_a = (const float*)d_in[12];
  const float* b_out = (const float*)d_in[13];
  // d_in[14..16] (Wt_r, Wt_a, b_t) are dead: hard gumbel = one_hot(argmax(logits+g)),
  // temp>0 never changes the argmax.
  const float* ln_g = (const float*)d_in[17];
  const float* ln_b = (const float*)d_in[18];
  const float* W_dec = (const float*)d_in[19];
  const float* b_dec = (const float*)d_in[20];
  float* out = (float*)d_out;

  float* ws = (float*)d_ws;
  size_t off = 0;
  _Float16* hnA1 = (_Float16*)(ws + off); off += (size_t)NN * DD / 2;
  _Float16* hnA2 = (_Float16*)(ws + off); off += (size_t)NN * DD / 2;
  _Float16* hnB1 = (_Float16*)(ws + off); off += (size_t)NN * DD / 2;
  _Float16* hnB2 = (_Float16*)(ws + off); off += (size_t)NN * DD / 2;
  _Float16* agg1 = (_Float16*)(ws + off); off += (size_t)NN * DD / 2;
  _Float16* agg2 = (_Float16*)(ws + off); off += (size_t)NN * DD / 2;
  float* SR = ws + off; off += (size_t)NN * 4;
  float* SA = ws + off; off += (size_t)NN * 4;
  int* rowptr = (int*)(ws + off); off += (size_t)NN + 4;
  int* csr_v = (int*)(ws + off);  off += (size_t)EE;
  unsigned char* gin = (unsigned char*)(ws + off);  off += (size_t)NN / 4;
  unsigned char* gout = (unsigned char*)(ws + off); off += (size_t)NN / 4;
  _Float16* cW1 = (_Float16*)(ws + off); off += (size_t)NLAYERS * DD * DD;  // [3][256][512]
  _Float16* cW2 = (_Float16*)(ws + off); off += (size_t)NLAYERS * DD * DD;
  _Float16* eW1 = (_Float16*)(ws + off); off += (size_t)DD * DIN / 2;       // [256][128]
  _Float16* eW2 = (_Float16*)(ws + off); off += (size_t)DD * DIN / 2;
  _Float16* dW1 = (_Float16*)(ws + off); off += (size_t)DOUT * DD / 2;      // [64][256]
  _Float16* dW2 = (_Float16*)(ws + off); off += (size_t)DOUT * DD / 2;
  if (ws_size < off * sizeof(float)) return;  // insufficient scratch -> visible failure
  // CSR-build aliases (SR/SA rewritten by the encoder epilogue after build)
  int* deg = (int*)SR;
  int* bsum = (int*)SR + NN;
  int* boffp = (int*)SR + NN + 256;
  int* cursor = (int*)SA;

  k_zero_deg<<<(NN + 255) / 256, 256, 0, stream>>>(deg);
  k_deg<<<(EE + 255) / 256, 256, 0, stream>>>(ei, deg);
  k_scan1<<<NB_SCAN, 256, 0, stream>>>(deg, bsum);
  k_scan2<<<1, 256, 0, stream>>>(bsum, boffp, rowptr);
  k_scan3<<<NB_SCAN, 256, 0, stream>>>(deg, boffp, rowptr, cursor);
  k_fill<<<(EE + 255) / 256, 256, 0, stream>>>(ei, cursor, csr_v);

  k_prep_conv<<<(NLAYERS * DD * 2 * DD + 255) / 256, 256, 0, stream>>>(W_root, W_agg, cW1, cW2);
  k_prep_ed<<<(DIN * DD + DD * DOUT + 255) / 256, 256, 0, stream>>>(W_enc, W_dec,
                                                                    eW1, eW2, dW1, dW2);

  const int gb = (NN + 63) / 64;
  // encoder fused: hn = LN(relu(x @ W_enc + b_enc)), + SR/SA
  k_gemm<DIN, 8, true, true, false, true><<<gb, 256, 0, stream>>>(
      x, nullptr, nullptr, nullptr, nullptr, eW1, eW2, b_enc,
      ln_g, ln_b, Wa_in_r, Wa_in_a, Wa_out_r, Wa_out_a,
      hnA1, hnA2, SR, SA, nullptr, 0);

  _Float16 *cur1 = hnA1, *cur2 = hnA2, *nxt1 = hnB1, *nxt2 = hnB2;
  for (int l = 0; l < NLAYERS; ++l) {
    k_gates_csr<<<(NN + 255) / 256, 256, 0, stream>>>(rowptr, csr_v, SR, SA, gn,
                                                      b_in, b_out, gin, gout, l);
    k_wagg_csr<<<(NN + 3) / 4, 256, 0, stream>>>(rowptr, csr_v, gin, gout,
                                                 cur1, cur2, agg1, agg2);
    // conv fused: hn' = LN(relu([hn|agg] @ [Wr;Wa] + b_env)), + SR/SA
    k_gemm<2 * DD, 8, true, false, true, true><<<gb, 256, 0, stream>>>(
        nullptr, cur1, cur2, agg1, agg2,
        cW1 + (size_t)l * DD * 2 * DD, cW2 + (size_t)l * DD * 2 * DD,
        b_env + (size_t)l * DD,
        ln_g, ln_b, Wa_in_r, Wa_in_a, Wa_out_r, Wa_out_a,
        nxt1, nxt2, SR, SA, nullptr, 0);
    _Float16* t1 = cur1; cur1 = nxt1; nxt1 = t1;
    _Float16* t2 = cur2; cur2 = nxt2; nxt2 = t2;
  }

  // decoder: out = hn @ W_dec + b_dec
  k_gemm<DD, 2, false, false, false, false><<<gb, 256, 0, stream>>>(
      nullptr, cur1, cur2, nullptr, nullptr, dW1, dW2, b_dec,
      nullptr, nullptr, nullptr, nullptr, nullptr, nullptr,
      nullptr, nullptr, nullptr, nullptr, out, DOUT);
}